// Round 1
// baseline (294.108 us; speedup 1.0000x reference)
//
#include <hip/hip_runtime.h>

// LocalCorrelation on MI355X (gfx950).
// Pass 1: fused L2-normalize (fp32 sumsq) + cast f16 + transpose to pixel-major [b][h][w][c].
// Pass 2: band-GEMM with mfma_f32_16x16x32_f16; block = (batch, 4 h-rows, 16 w-cols),
//         waves iterate over b-rows jj so each B-frag feeds 4 MFMAs (rows r=0..3, dy=jj-6-r).
// Epilogue scatters the 16x28 band into LDS [k][r][16+pad] then stores coalesced.
// Workspace: 2 * 4*128*128*256 f16 = 67.1 MB.

typedef _Float16 half8 __attribute__((ext_vector_type(8)));
typedef float floatx4 __attribute__((ext_vector_type(4)));

#define B_ 4
#define C_ 256
#define H_ 128
#define W_ 128
#define K2_ 169
#define INV_T 14.285714285714286f

// ---------------- Pass 1: normalize + transpose ----------------
__global__ __launch_bounds__(256) void nt_kernel(const float* __restrict__ fa,
                                                 const float* __restrict__ fb,
                                                 _Float16* __restrict__ an,
                                                 _Float16* __restrict__ bn) {
  __shared__ float tile[256 * 33];  // [c][w(32)+1 pad] -> 33.8 KB
  __shared__ float ps[256];
  __shared__ float invn[32];
  const int bid = blockIdx.x;
  const int wc   = bid & 3;          // w-chunk of 32
  const int h    = (bid >> 2) & 127;
  const int bb   = (bid >> 9) & 3;
  const int tens = bid >> 11;        // 0 = a, 1 = b
  const float* __restrict__ src = tens ? fb : fa;
  _Float16* __restrict__ dst    = tens ? bn : an;
  const int t = threadIdx.x;
  const int w = t & 31, cp = t >> 5;

  #pragma unroll 4
  for (int it = 0; it < 32; ++it) {
    const int c = it * 8 + cp;
    tile[c * 33 + w] = src[(((size_t)bb * C_ + c) * H_ + h) * W_ + wc * 32 + w];
  }
  __syncthreads();

  float ss = 0.f;
  #pragma unroll
  for (int j = 0; j < 32; ++j) {
    const float v = tile[(cp * 32 + j) * 33 + w];
    ss += v * v;
  }
  ps[cp * 32 + w] = ss;
  __syncthreads();
  if (t < 32) {
    float s2 = 0.f;
    #pragma unroll
    for (int p = 0; p < 8; ++p) s2 += ps[p * 32 + t];
    invn[t] = 1.0f / fmaxf(sqrtf(s2), 1e-12f);  // matches F.normalize eps semantics
  }
  __syncthreads();

  // transposed write: thread (w2, seg) packs 32 channels -> 4x uint4 contiguous stores
  const int w2 = t >> 3, seg = t & 7;
  const float inv = invn[w2];
  _Float16* __restrict__ dp =
      dst + (((size_t)bb * H_ + h) * W_ + wc * 32 + w2) * C_ + seg * 32;
  #pragma unroll
  for (int blk = 0; blk < 4; ++blk) {
    _Float16 tmp[8] __attribute__((aligned(16)));
    #pragma unroll
    for (int j = 0; j < 8; ++j) {
      const int c = seg * 32 + blk * 8 + j;
      tmp[j] = (_Float16)(tile[c * 33 + w2] * inv);
    }
    *(uint4*)(dp + blk * 8) = *(const uint4*)tmp;
  }
}

// ---------------- Pass 2: band-GEMM correlation ----------------
// LDS layouts:
//  a: [px(4r*16m)][k(32)]          -> A-frag read = ds_read_b128 at ((r*16+m)*32 + q*8)
//  b: [g=k>>3][px(16row*28col)][8] -> B-frag read = ds_read_b128 at ((q*448 + row*28 + col)*8)
struct StageS { _Float16 a[2048]; _Float16 b[14336 + 384]; };  // pad: frag reads at col 28..31 (discarded) stay in-array
union SmemU { StageS s; float ostage[676 * 17]; };            // 45.97 KB

__global__ __launch_bounds__(256) void corr_kernel(const _Float16* __restrict__ an,
                                                   const _Float16* __restrict__ bn,
                                                   float* __restrict__ out) {
  __shared__ SmemU u;
  const int bid = blockIdx.x;
  // XCD swizzle: bid%8 is the XCD (round-robin dispatch) -> give each XCD a contiguous h-band
  const int xcd = bid & 7, l = bid >> 3;
  const int bb = l >> 5, hg = xcd * 4 + ((l >> 3) & 3), wt = l & 7;
  const int h0 = hg * 4, w0 = wt * 16;
  const int t = threadIdx.x;
  const int lane = t & 63, v = t >> 6;   // wave id 0..3
  const int ml = lane & 15, q = lane >> 4;

  floatx4 acc[4][2][4] = {};  // [u4 -> jj=v+4*u4][ntile][r]; 13 of 16 (jj,r) pairs valid per wave

  const int apx = t >> 2, asg = t & 3;
  const int ar = apx >> 4, am = apx & 15;
  const _Float16* aptr =
      an + (((size_t)bb * H_ + h0 + ar) * W_ + w0 + am) * C_ + asg * 8;

  for (int k0 = 0; k0 < C_; k0 += 32) {
    __syncthreads();
    // stage a: 64 px * 32 k, one uint4 per thread
    *(uint4*)(u.s.a + apx * 32 + asg * 8) = *(const uint4*)(aptr + k0);
    // stage b halo: 16 rows (h0-6..h0+9) x 28 cols (w0-6..w0+21) x 32 k = 1792 uint4
    #pragma unroll
    for (int e = 0; e < 7; ++e) {
      const int i = t + 256 * e;
      const int px = i >> 2, sg = i & 3;
      const int row = px / 28, col = px - row * 28;
      const int rim = h0 - 6 + row, cim = w0 - 6 + col;
      uint4 val = make_uint4(0u, 0u, 0u, 0u);  // zero-pad OOB (matches reference padding)
      if ((unsigned)rim < (unsigned)H_ && (unsigned)cim < (unsigned)W_)
        val = *(const uint4*)(bn + (((size_t)bb * H_ + rim) * W_ + cim) * C_ + k0 + sg * 8);
      *(uint4*)(u.s.b + (sg * 448 + px) * 8) = val;
    }
    __syncthreads();

    half8 A[4];
    #pragma unroll
    for (int r = 0; r < 4; ++r)
      A[r] = *(const half8*)(u.s.a + (r * 16 + ml) * 32 + q * 8);

    #pragma unroll
    for (int u4 = 0; u4 < 4; ++u4) {
      const int jj = v + u4 * 4;  // staged b-row index 0..15 (image row h0+jj-6)
      #pragma unroll
      for (int nt = 0; nt < 2; ++nt) {
        const half8 Bf = *(const half8*)(u.s.b + (q * 448 + jj * 28 + nt * 16 + ml) * 8);
        #pragma unroll
        for (int r = 0; r < 4; ++r) {
          // dy = jj - 6 - r must be in [-6,6]  <=>  r <= jj <= r+12  (wave-uniform branch)
          if (jj >= r && jj <= r + 12)
            acc[u4][nt][r] =
                __builtin_amdgcn_mfma_f32_16x16x32_f16(A[r], Bf, acc[u4][nt][r], 0, 0, 0);
        }
      }
    }
  }
  __syncthreads();  // all frag reads done before ostage overwrites staging

  // epilogue: C/D layout col=lane&15, row=(lane>>4)*4+p. D[i][jcol]: i = w-pixel, jcol = halo col.
  // dx+6 = jcol - i in [0,12]; dy+6 = jj - r in [0,12].
  #pragma unroll
  for (int u4 = 0; u4 < 4; ++u4) {
    const int jj = v + u4 * 4;
    #pragma unroll
    for (int nt = 0; nt < 2; ++nt) {
      const int col = nt * 16 + ml;
      #pragma unroll
      for (int r = 0; r < 4; ++r) {
        const int dy6 = jj - r;
        if (dy6 >= 0 && dy6 <= 12) {
          #pragma unroll
          for (int p = 0; p < 4; ++p) {
            const int ip = q * 4 + p;
            const int dx6 = col - ip;
            if (dx6 >= 0 && dx6 <= 12)
              u.ostage[((dy6 * 13 + dx6) * 4 + r) * 17 + ip] = acc[u4][nt][r][p] * INV_T;
          }
        }
      }
    }
  }
  __syncthreads();

  // coalesced store: 16 lanes = one (k, r) 64B segment
  for (int sidx = t; sidx < K2_ * 64; sidx += 256) {
    const int k = sidx >> 6, rem = sidx & 63, r = rem >> 4, ip = rem & 15;
    out[(((size_t)bb * K2_ + k) * H_ + h0 + r) * W_ + w0 + ip] =
        u.ostage[(k * 4 + r) * 17 + ip];
  }
}

extern "C" void kernel_launch(void* const* d_in, const int* in_sizes, int n_in,
                              void* d_out, int out_size, void* d_ws, size_t ws_size,
                              hipStream_t stream) {
  const float* fa = (const float*)d_in[0];
  const float* fb = (const float*)d_in[1];
  float* out = (float*)d_out;
  _Float16* an = (_Float16*)d_ws;                       // 33.55 MB
  _Float16* bn = an + (size_t)B_ * H_ * W_ * C_;        // 33.55 MB (total 67.1 MB of ws)
  nt_kernel<<<2 * B_ * H_ * 4, 256, 0, stream>>>(fa, fb, an, bn);
  corr_kernel<<<B_ * 32 * 8, 256, 0, stream>>>(an, bn, out);
}

// Round 2
// 219.614 us; speedup vs baseline: 1.3392x; 1.3392x over previous
//
#include <hip/hip_runtime.h>

// LocalCorrelation on MI355X (gfx950).  R2.
// Pass 1: fused L2-normalize (fp32 sumsq) + cast f16 + transpose to pixel-major [b][h][w][c].
// Pass 2: band-GEMM, mfma_f32_16x16x32_f16. Block = (batch, 2 h-rows, 16 w), 4 waves.
//   Wave wv: nt = wv&1 (halo-col tile), jjg = wv>>1; jj = jjg + 2u (7 strided b-rows).
//   acc[7][2] = 56 VGPRs (R1 had 128 -> 1 wave/SIMD, the occupancy collapse).
// LDS strides padded to odd*16B (bank offset 20) to kill R1's 2.07e7 bank conflicts.
// Staging = 7 precomputed jobs/thread (ptr, ldsoff, valid bit); k-loop fully unrolled.

typedef _Float16 half8 __attribute__((ext_vector_type(8)));
typedef float floatx4 __attribute__((ext_vector_type(4)));

#define B_ 4
#define C_ 256
#define H_ 128
#define W_ 128
#define K2_ 169
#define INV_T 14.285714285714286f

// ---------------- Pass 1: normalize + transpose ----------------
__global__ __launch_bounds__(256) void nt_kernel(const float* __restrict__ fa,
                                                 const float* __restrict__ fb,
                                                 _Float16* __restrict__ an,
                                                 _Float16* __restrict__ bn) {
  __shared__ float tile[256 * 33];  // [c][w(32)+1 pad]
  __shared__ float ps[256];
  __shared__ float invn[32];
  const int bid = blockIdx.x;
  const int wc   = bid & 3;
  const int h    = (bid >> 2) & 127;
  const int bb   = (bid >> 9) & 3;
  const int tens = bid >> 11;        // 0 = a, 1 = b
  const float* __restrict__ src = tens ? fb : fa;
  _Float16* __restrict__ dst    = tens ? bn : an;
  const int t = threadIdx.x;
  const int w = t & 31, cp = t >> 5;

  #pragma unroll 4
  for (int it = 0; it < 32; ++it) {
    const int c = it * 8 + cp;
    tile[c * 33 + w] = src[(((size_t)bb * C_ + c) * H_ + h) * W_ + wc * 32 + w];
  }
  __syncthreads();

  float ss = 0.f;
  #pragma unroll
  for (int j = 0; j < 32; ++j) {
    const float v = tile[(cp * 32 + j) * 33 + w];
    ss += v * v;
  }
  ps[cp * 32 + w] = ss;
  __syncthreads();
  if (t < 32) {
    float s2 = 0.f;
    #pragma unroll
    for (int p = 0; p < 8; ++p) s2 += ps[p * 32 + t];
    invn[t] = 1.0f / fmaxf(sqrtf(s2), 1e-12f);
  }
  __syncthreads();

  const int w2 = t >> 3, seg = t & 7;
  const float inv = invn[w2];
  _Float16* __restrict__ dp =
      dst + (((size_t)bb * H_ + h) * W_ + wc * 32 + w2) * C_ + seg * 32;
  #pragma unroll
  for (int blk = 0; blk < 4; ++blk) {
    _Float16 tmp[8] __attribute__((aligned(16)));
    #pragma unroll
    for (int j = 0; j < 8; ++j) {
      const int c = seg * 32 + blk * 8 + j;
      tmp[j] = (_Float16)(tile[c * 33 + w2] * inv);
    }
    *(uint4*)(dp + blk * 8) = *(const uint4*)tmp;
  }
}

// ---------------- Pass 2: band-GEMM correlation ----------------
// LDS (halfword offsets):
//   a: [0, 1280)        a[px*40 + sg*8], px = r*16 + m (stride 40 -> bank offset 20/dword)
//   b: [1280, 13992)    b[sg*3176 + px*8], px = row*28 + col (stride 3176 -> bank offset 20)
//   dummy slot at 1280 + 12704 for padded jobs
// real b writes end at 12656+8; frag reads (col<=31 overread, discarded) end at 12696 <= 12704.
struct StageS { _Float16 a[1280]; _Float16 b[12712]; };   // 27,984 B
union SmemU { StageS s; float ostage[169 * 2 * 17]; };    // ostage 22,984 B

__global__ __launch_bounds__(256, 3) void corr_kernel(const _Float16* __restrict__ an,
                                                      const _Float16* __restrict__ bn,
                                                      float* __restrict__ out) {
  __shared__ SmemU u;
  const int bid = blockIdx.x;
  // XCD swizzle: bid&7 = XCD -> each XCD owns a contiguous h-band (L2 locality)
  const int xcd = bid & 7, l = bid >> 3;
  const int bb = l >> 6, hseg = (l >> 3) & 7, wt = l & 7;
  const int hg = xcd * 8 + hseg;
  const int h0 = hg * 2, w0 = wt * 16;
  const int t = threadIdx.x;
  const int lane = t & 63, wv = t >> 6;
  const int ml = lane & 15, q = lane >> 4;
  const int nt = wv & 1, jjg = wv >> 1;   // wave's halo-col tile & jj parity

  _Float16* const smem = (_Float16*)&u.s;

  // ---- build job table once (R1 recomputed div/28 + bounds every k-iter) ----
  const _Float16* gptr[7];
  int loff[7];
  unsigned flags = 0u;
  #pragma unroll
  for (int j = 0; j < 7; ++j) {
    const int job = j * 256 + t;
    if (job < 1568) {            // b-halo: 392 px (14 rows x 28 cols) x 4 k-chunks
      const int px = job >> 2, sg = job & 3;
      const int row = px / 28, col = px - row * 28;
      const int rim = h0 - 6 + row, cim = w0 - 6 + col;
      const bool ok = ((unsigned)rim < (unsigned)H_) && ((unsigned)cim < (unsigned)W_);
      const int rr = ok ? rim : 0, cc = ok ? cim : 0;
      gptr[j] = bn + (((size_t)bb * H_ + rr) * W_ + cc) * C_ + sg * 8;
      loff[j] = 1280 + sg * 3176 + px * 8;
      if (ok) flags |= 1u << j;
    } else if (job < 1696) {     // a-tile: 32 px (2 rows x 16 w) x 4 k-chunks
      const int jb = job - 1568;
      const int px = jb >> 2, sg = jb & 3;
      const int rr = px >> 4, m = px & 15;
      gptr[j] = an + (((size_t)bb * H_ + h0 + rr) * W_ + w0 + m) * C_ + sg * 8;
      loff[j] = px * 40 + sg * 8;
      flags |= 1u << j;
    } else {                     // padding job -> zero write to dummy slot
      gptr[j] = an;
      loff[j] = 1280 + 12704;
    }
  }

  floatx4 acc[7][2] = {};        // [u: jj=jjg+2u][r]; 13 of 14 slots valid per wave

  #pragma unroll
  for (int k0 = 0; k0 < C_; k0 += 32) {
    __syncthreads();
    #pragma unroll
    for (int j = 0; j < 7; ++j) {
      uint4 v = make_uint4(0u, 0u, 0u, 0u);
      if (flags & (1u << j)) v = *(const uint4*)(gptr[j] + k0);
      *(uint4*)(smem + loff[j]) = v;
    }
    __syncthreads();

    const half8 A0 = *(const half8*)(smem + ml * 40 + q * 8);          // out-row r=0
    const half8 A1 = *(const half8*)(smem + (16 + ml) * 40 + q * 8);   // out-row r=1
    #pragma unroll
    for (int uu = 0; uu < 7; ++uu) {
      const int jj = jjg + 2 * uu;
      const half8 Bf =
          *(const half8*)(smem + 1280 + q * 3176 + (jj * 28 + nt * 16 + ml) * 8);
      // r=0 valid unless jj==13 (uu==6 && jjg==1); r=1 valid unless jj==0 (uu==0 && jjg==0)
      if (uu != 6 || jjg == 0)
        acc[uu][0] = __builtin_amdgcn_mfma_f32_16x16x32_f16(A0, Bf, acc[uu][0], 0, 0, 0);
      if (uu != 0 || jjg == 1)
        acc[uu][1] = __builtin_amdgcn_mfma_f32_16x16x32_f16(A1, Bf, acc[uu][1], 0, 0, 0);
    }
  }
  __syncthreads();

  // ---- epilogue: C/D layout col=lane&15, row=(lane>>4)*4+p ----
  #pragma unroll
  for (int uu = 0; uu < 7; ++uu) {
    const int jj = jjg + 2 * uu;
    #pragma unroll
    for (int r = 0; r < 2; ++r) {
      if (uu == 6 && r == 0 && jjg == 1) continue;
      if (uu == 0 && r == 1 && jjg == 0) continue;
      const int dy6 = jj - r;               // 0..12
      const int col = nt * 16 + ml;
      #pragma unroll
      for (int p = 0; p < 4; ++p) {
        const int ip = q * 4 + p;
        const int dx6 = col - ip;
        if (dx6 >= 0 && dx6 <= 12)
          u.ostage[((dy6 * 13 + dx6) * 2 + r) * 17 + ip] = acc[uu][r][p] * INV_T;
      }
    }
  }
  __syncthreads();

  for (int sidx = t; sidx < K2_ * 32; sidx += 256) {
    const int k = sidx >> 5, rem = sidx & 31, r = rem >> 4, ip = rem & 15;
    out[(((size_t)bb * K2_ + k) * H_ + h0 + r) * W_ + w0 + ip] =
        u.ostage[(k * 2 + r) * 17 + ip];
  }
}

extern "C" void kernel_launch(void* const* d_in, const int* in_sizes, int n_in,
                              void* d_out, int out_size, void* d_ws, size_t ws_size,
                              hipStream_t stream) {
  const float* fa = (const float*)d_in[0];
  const float* fb = (const float*)d_in[1];
  float* out = (float*)d_out;
  _Float16* an = (_Float16*)d_ws;                       // 33.55 MB
  _Float16* bn = an + (size_t)B_ * H_ * W_ * C_;        // 33.55 MB
  nt_kernel<<<2 * B_ * H_ * 4, 256, 0, stream>>>(fa, fb, an, bn);
  corr_kernel<<<B_ * 64 * 8, 256, 0, stream>>>(an, bn, out);
}